// Round 1
// baseline (4514.521 us; speedup 1.0000x reference)
//
#include <hip/hip_runtime.h>
#include <math.h>

// ---------------- problem constants ----------------
#define DD 768
#define NHEAD 12
#define HDIM 64
#define NTOK 197
#define BB 8
#define TT (BB*NTOK)          // 1576 tokens
#define NPATCH 196
#define TP (BB*NPATCH)        // 1568 patch rows
#define HID 3072
#define NEXP 8
#define NCLS 1000
#define QKVN (3*DD)           // 2304
#define MAXA 3712             // 58*64 padded MoE assignment capacity (2*TT + 8*63 <= 3656)
#define NAT 58                // MoE row tiles

// epilogue flags
#define F_BIAS 1
#define F_GELU 2
#define F_RESID 4

__device__ __forceinline__ float gelu_f(float x) {
  return 0.5f * x * (1.0f + erff(x * 0.70710678118654752f));
}

// ---------------- patchify: x[B,3,224,224] -> pm[1568,768] ----------------
__global__ void patchify_k(const float* __restrict__ x, float* __restrict__ pm) {
  int idx = blockIdx.x * 256 + threadIdx.x;
  if (idx >= TP * DD) return;
  int cidx = idx % DD;
  int row  = idx / DD;
  int b = row / NPATCH, p = row % NPATCH;
  int c = cidx >> 8;          // 0..2
  int rem = cidx & 255;
  int i = rem >> 4, j = rem & 15;
  int gy = p / 14, gx = p % 14;
  pm[idx] = x[((size_t)(b*3 + c)*224 + gy*16 + i)*224 + gx*16 + j];
}

// ---------------- assemble h: cls+pos / tok+pos ----------------
__global__ void assemble_k(const float* __restrict__ tok, const float* __restrict__ cls,
                           const float* __restrict__ pos, float* __restrict__ h) {
  int idx = blockIdx.x * 256 + threadIdx.x;
  if (idx >= TT * DD) return;
  int c = idx % DD;
  int row = idx / DD;
  int b = row / NTOK, n = row % NTOK;
  float v;
  if (n == 0) v = cls[c] + pos[c];
  else        v = tok[((size_t)(b*NPATCH + n - 1))*DD + c] + pos[(size_t)n*DD + c];
  h[idx] = v;
}

// ---------------- layernorm: 768 = 3*256 ----------------
__global__ void ln_k(const float* __restrict__ in, size_t in_stride,
                     const float* __restrict__ g, const float* __restrict__ bta,
                     float* __restrict__ out, int nrows) {
  int r = blockIdx.x;
  if (r >= nrows) return;
  const float* xr = in + (size_t)r * in_stride;
  float* o = out + (size_t)r * DD;
  __shared__ float red[256];
  int tid = threadIdx.x;
  float v0 = xr[tid], v1 = xr[tid+256], v2 = xr[tid+512];
  red[tid] = v0 + v1 + v2; __syncthreads();
  for (int st = 128; st > 0; st >>= 1) { if (tid < st) red[tid] += red[tid+st]; __syncthreads(); }
  float mean = red[0] * (1.0f/768.0f); __syncthreads();
  float d0 = v0-mean, d1 = v1-mean, d2 = v2-mean;
  red[tid] = d0*d0 + d1*d1 + d2*d2; __syncthreads();
  for (int st = 128; st > 0; st >>= 1) { if (tid < st) red[tid] += red[tid+st]; __syncthreads(); }
  float rstd = rsqrtf(red[0] * (1.0f/768.0f) + 1e-5f);
  o[tid]     = d0*rstd*g[tid]     + bta[tid];
  o[tid+256] = d1*rstd*g[tid+256] + bta[tid+256];
  o[tid+512] = d2*rstd*g[tid+512] + bta[tid+512];
}

// ---------------- generic tiled GEMM: C[M,N] = epi(A[M,K] @ B[K,N]) ----------------
// BM=BN=64, BK=16, 256 threads, 4x4 micro-tile
__global__ void gemm_k(const float* __restrict__ A, const float* __restrict__ Bm,
                       const float* __restrict__ bias, const float* __restrict__ resid,
                       float* __restrict__ C, int M, int N, int K, int flags) {
  __shared__ float As[16][68];
  __shared__ float Bs[16][64];
  int tid = threadIdx.x;
  int tr = tid >> 4, tc = tid & 15;
  int row0 = blockIdx.y << 6;
  int col0 = blockIdx.x << 6;
  float acc[4][4] = {};
  for (int k0 = 0; k0 < K; k0 += 16) {
    #pragma unroll
    for (int i = 0; i < 4; i++) {
      int r = (tid >> 4) + (i << 4);
      int c = tid & 15;
      int gr = row0 + r;
      As[c][r] = (gr < M) ? A[(size_t)gr*K + k0 + c] : 0.0f;
    }
    #pragma unroll
    for (int i = 0; i < 4; i++) {
      int l = tid + (i << 8);
      int r = l >> 6, c = l & 63;
      int gc = col0 + c;
      Bs[r][c] = (gc < N) ? Bm[(size_t)(k0 + r)*N + gc] : 0.0f;
    }
    __syncthreads();
    #pragma unroll
    for (int kk = 0; kk < 16; kk++) {
      const float4 av = *reinterpret_cast<const float4*>(&As[kk][tr << 2]);
      const float4 bv = *reinterpret_cast<const float4*>(&Bs[kk][tc << 2]);
      float a4[4] = {av.x, av.y, av.z, av.w};
      float b4[4] = {bv.x, bv.y, bv.z, bv.w};
      #pragma unroll
      for (int i = 0; i < 4; i++)
        #pragma unroll
        for (int j = 0; j < 4; j++)
          acc[i][j] += a4[i] * b4[j];
    }
    __syncthreads();
  }
  #pragma unroll
  for (int i = 0; i < 4; i++) {
    int r = row0 + (tr << 2) + i;
    if (r >= M) continue;
    #pragma unroll
    for (int j = 0; j < 4; j++) {
      int c = col0 + (tc << 2) + j;
      if (c >= N) continue;
      float v = acc[i][j];
      if (flags & F_BIAS)  v += bias[c];
      if (flags & F_GELU)  v = gelu_f(v);
      if (flags & F_RESID) v += resid[(size_t)r*N + c];
      C[(size_t)r*N + c] = v;
    }
  }
}

// ---------------- attention: one block per (query, b*head) ----------------
__global__ void attn_k(const float* __restrict__ qkv, float* __restrict__ out) {
  int n  = blockIdx.x;
  int bh = blockIdx.y;
  int b = bh / NHEAD, hh = bh % NHEAD;
  const float* base = qkv + (size_t)b * NTOK * QKVN;
  __shared__ float q[HDIM];
  __shared__ float sc[NTOK];
  __shared__ float red[256];
  int tid = threadIdx.x;
  if (tid < HDIM) q[tid] = base[(size_t)n*QKVN + hh*HDIM + tid];
  __syncthreads();
  for (int jj = tid; jj < NTOK; jj += 256) {
    const float* kr = base + (size_t)jj*QKVN + DD + hh*HDIM;
    float s = 0.0f;
    #pragma unroll
    for (int d = 0; d < HDIM; d++) s += q[d] * kr[d];
    sc[jj] = s * 0.125f;
  }
  __syncthreads();
  float m = -1e30f;
  for (int jj = tid; jj < NTOK; jj += 256) m = fmaxf(m, sc[jj]);
  red[tid] = m; __syncthreads();
  for (int st = 128; st > 0; st >>= 1) { if (tid < st) red[tid] = fmaxf(red[tid], red[tid+st]); __syncthreads(); }
  m = red[0]; __syncthreads();
  float sum = 0.0f;
  for (int jj = tid; jj < NTOK; jj += 256) { float ev = expf(sc[jj] - m); sc[jj] = ev; sum += ev; }
  red[tid] = sum; __syncthreads();
  for (int st = 128; st > 0; st >>= 1) { if (tid < st) red[tid] += red[tid+st]; __syncthreads(); }
  float inv = 1.0f / red[0];
  __syncthreads();
  int d = tid & 63, j4 = tid >> 6;
  float acc = 0.0f;
  for (int jj = j4; jj < NTOK; jj += 4)
    acc += sc[jj] * base[(size_t)jj*QKVN + 2*DD + hh*HDIM + d];
  red[tid] = acc; __syncthreads();
  if (tid < 64) {
    float o = (red[tid] + red[tid+64] + red[tid+128] + red[tid+192]) * inv;
    out[((size_t)b*NTOK + n)*DD + hh*HDIM + d] = o;
  }
}

// ---------------- MoE routing ----------------
__global__ void zero_k(int* __restrict__ cnt) {
  if (threadIdx.x < 16) cnt[threadIdx.x] = 0;   // cnt[8] + cnt2[8] contiguous
}

__global__ void gate_k(const float* __restrict__ xln, const float* __restrict__ wg,
                       int* __restrict__ e01, float* __restrict__ g01, int* __restrict__ cnt) {
  int t = blockIdx.x * 64 + threadIdx.x;
  if (t >= TT) return;
  float lg[NEXP] = {};
  const float* xr = xln + (size_t)t * DD;
  for (int k = 0; k < DD; k++) {
    float xv = xr[k];
    const float* wr = wg + (size_t)k * NEXP;
    #pragma unroll
    for (int e = 0; e < NEXP; e++) lg[e] += xv * wr[e];
  }
  int e0 = 0; float v0 = lg[0];
  #pragma unroll
  for (int e = 1; e < NEXP; e++) if (lg[e] > v0) { v0 = lg[e]; e0 = e; }
  int e1 = -1; float v1 = -1e30f;
  #pragma unroll
  for (int e = 0; e < NEXP; e++) if (e != e0 && lg[e] > v1) { v1 = lg[e]; e1 = e; }
  float g0 = 1.0f / (1.0f + expf(v1 - v0));
  float g1 = 1.0f - g0;
  e01[t*2]   = e0; e01[t*2+1] = e1;
  g01[t*2]   = g0; g01[t*2+1] = g1;
  atomicAdd(&cnt[e0], 1);
  atomicAdd(&cnt[e1], 1);
}

__global__ void offs_k(const int* __restrict__ cnt, int* __restrict__ offs) {
  if (threadIdx.x == 0 && blockIdx.x == 0) {
    int acc = 0;
    for (int e = 0; e < NEXP; e++) {
      offs[e] = acc;
      acc += ((cnt[e] + 63) >> 6) << 6;
    }
    offs[NEXP] = acc;
  }
}

__global__ void scatter_k(const int* __restrict__ e01, const float* __restrict__ g01,
                          const int* __restrict__ offs, int* __restrict__ cnt2,
                          int* __restrict__ tok_l, float* __restrict__ gate_l,
                          int* __restrict__ slot_l) {
  int t = blockIdx.x * 64 + threadIdx.x;
  if (t >= TT) return;
  #pragma unroll
  for (int s = 0; s < 2; s++) {
    int e = e01[t*2+s];
    int pos = atomicAdd(&cnt2[e], 1);
    int a = offs[e] + pos;
    tok_l[a] = t;
    gate_l[a] = g01[t*2+s];
    slot_l[a] = s;
  }
}

// ---------------- MoE expert GEMM1: Hb[a,:] = gelu(x[tok[a]] @ W1[e] + b1[e]) ----------------
__global__ void moe_gemm1_k(const float* __restrict__ X, const float* __restrict__ W1,
                            const float* __restrict__ B1, const int* __restrict__ offs,
                            const int* __restrict__ cnt, const int* __restrict__ tok_l,
                            float* __restrict__ Hb) {
  __shared__ float As[16][68];
  __shared__ float Bs[16][64];
  int row0 = blockIdx.y << 6;
  int total = offs[NEXP];
  if (row0 >= total) return;
  int e = 0;
  #pragma unroll
  for (int q = 1; q < NEXP; q++) if (row0 >= offs[q]) e = q;
  int vend = offs[e] + cnt[e];
  const float* Bm = W1 + (size_t)e * DD * HID;
  const float* bias = B1 + (size_t)e * HID;
  int col0 = blockIdx.x << 6;
  int tid = threadIdx.x;
  int tr = tid >> 4, tc = tid & 15;
  int tl4[4]; bool vr4[4];
  #pragma unroll
  for (int i = 0; i < 4; i++) {
    int a = row0 + (tid >> 4) + (i << 4);
    vr4[i] = (a < vend);
    tl4[i] = vr4[i] ? tok_l[a] : 0;
  }
  float acc[4][4] = {};
  int cA = tid & 15;
  for (int k0 = 0; k0 < DD; k0 += 16) {
    #pragma unroll
    for (int i = 0; i < 4; i++) {
      int r = (tid >> 4) + (i << 4);
      As[cA][r] = vr4[i] ? X[(size_t)tl4[i]*DD + k0 + cA] : 0.0f;
    }
    #pragma unroll
    for (int i = 0; i < 4; i++) {
      int l = tid + (i << 8);
      int r = l >> 6, c = l & 63;
      Bs[r][c] = Bm[(size_t)(k0 + r)*HID + col0 + c];
    }
    __syncthreads();
    #pragma unroll
    for (int kk = 0; kk < 16; kk++) {
      const float4 av = *reinterpret_cast<const float4*>(&As[kk][tr << 2]);
      const float4 bv = *reinterpret_cast<const float4*>(&Bs[kk][tc << 2]);
      float a4[4] = {av.x, av.y, av.z, av.w};
      float b4[4] = {bv.x, bv.y, bv.z, bv.w};
      #pragma unroll
      for (int i = 0; i < 4; i++)
        #pragma unroll
        for (int j = 0; j < 4; j++)
          acc[i][j] += a4[i] * b4[j];
    }
    __syncthreads();
  }
  #pragma unroll
  for (int i = 0; i < 4; i++) {
    int a = row0 + (tr << 2) + i;
    bool v = (a < vend);
    #pragma unroll
    for (int j = 0; j < 4; j++) {
      int c = col0 + (tc << 2) + j;
      Hb[(size_t)a*HID + c] = v ? gelu_f(acc[i][j] + bias[c]) : 0.0f;
    }
  }
}

// ---------------- MoE expert GEMM2: moe_out[tok,slot,:] = g * (Hb[a] @ W2[e] + b2[e]) -------
__global__ void moe_gemm2_k(const float* __restrict__ Hb, const float* __restrict__ W2,
                            const float* __restrict__ B2, const int* __restrict__ offs,
                            const int* __restrict__ cnt, const int* __restrict__ tok_l,
                            const int* __restrict__ slot_l, const float* __restrict__ gate_l,
                            float* __restrict__ moe_out) {
  __shared__ float As[16][68];
  __shared__ float Bs[16][64];
  int row0 = blockIdx.y << 6;
  int total = offs[NEXP];
  if (row0 >= total) return;
  int e = 0;
  #pragma unroll
  for (int q = 1; q < NEXP; q++) if (row0 >= offs[q]) e = q;
  int vend = offs[e] + cnt[e];
  const float* Bm = W2 + (size_t)e * HID * DD;
  const float* bias = B2 + (size_t)e * DD;
  int col0 = blockIdx.x << 6;
  int tid = threadIdx.x;
  int tr = tid >> 4, tc = tid & 15;
  float acc[4][4] = {};
  for (int k0 = 0; k0 < HID; k0 += 16) {
    #pragma unroll
    for (int i = 0; i < 4; i++) {
      int r = (tid >> 4) + (i << 4);
      As[tid & 15][r] = Hb[(size_t)(row0 + r)*HID + k0 + (tid & 15)];
    }
    #pragma unroll
    for (int i = 0; i < 4; i++) {
      int l = tid + (i << 8);
      int r = l >> 6, c = l & 63;
      Bs[r][c] = Bm[(size_t)(k0 + r)*DD + col0 + c];
    }
    __syncthreads();
    #pragma unroll
    for (int kk = 0; kk < 16; kk++) {
      const float4 av = *reinterpret_cast<const float4*>(&As[kk][tr << 2]);
      const float4 bv = *reinterpret_cast<const float4*>(&Bs[kk][tc << 2]);
      float a4[4] = {av.x, av.y, av.z, av.w};
      float b4[4] = {bv.x, bv.y, bv.z, bv.w};
      #pragma unroll
      for (int i = 0; i < 4; i++)
        #pragma unroll
        for (int j = 0; j < 4; j++)
          acc[i][j] += a4[i] * b4[j];
    }
    __syncthreads();
  }
  #pragma unroll
  for (int i = 0; i < 4; i++) {
    int a = row0 + (tr << 2) + i;
    if (a >= vend) continue;
    int t = tok_l[a];
    int s = slot_l[a];
    float g = gate_l[a];
    #pragma unroll
    for (int j = 0; j < 4; j++) {
      int c = col0 + (tc << 2) + j;
      moe_out[((size_t)t*2 + s)*DD + c] = g * (acc[i][j] + bias[c]);
    }
  }
}

__global__ void combine_k(const float* __restrict__ moe_out, float* __restrict__ h) {
  int idx = blockIdx.x * 256 + threadIdx.x;
  if (idx >= TT * DD) return;
  int c = idx % DD;
  int row = idx / DD;
  h[idx] += moe_out[((size_t)row*2)*DD + c] + moe_out[((size_t)row*2 + 1)*DD + c];
}

// ---------------- head: out[b,c] = clsln[b] . w_head[:,c] + b_head[c] ----------------
__global__ void head_k(const float* __restrict__ clsln, const float* __restrict__ w_head,
                       const float* __restrict__ b_head, float* __restrict__ out) {
  int id = blockIdx.x * 256 + threadIdx.x;
  if (id >= BB * NCLS) return;
  int b = id / NCLS, c = id % NCLS;
  float acc = b_head[c];
  const float* xr = clsln + (size_t)b * DD;
  for (int k = 0; k < DD; k++) acc += xr[k] * w_head[(size_t)k*NCLS + c];
  out[id] = acc;
}

// ---------------- host ----------------
extern "C" void kernel_launch(void* const* d_in, const int* in_sizes, int n_in,
                              void* d_out, int out_size, void* d_ws, size_t ws_size,
                              hipStream_t stream) {
  const float* x        = (const float*)d_in[0];
  const float* w_patch  = (const float*)d_in[1];
  const float* b_patch  = (const float*)d_in[2];
  const float* cls_tok  = (const float*)d_in[3];
  const float* pos_emb  = (const float*)d_in[4];
  const float* ln1_g    = (const float*)d_in[5];
  const float* ln1_b    = (const float*)d_in[6];
  const float* w_qkv    = (const float*)d_in[7];
  const float* w_proj   = (const float*)d_in[8];
  const float* b_proj   = (const float*)d_in[9];
  const float* ln2_g    = (const float*)d_in[10];
  const float* ln2_b    = (const float*)d_in[11];
  const float* w_fc1    = (const float*)d_in[12];
  const float* b_fc1    = (const float*)d_in[13];
  const float* w_fc2    = (const float*)d_in[14];
  const float* b_fc2    = (const float*)d_in[15];
  const float* w_gate   = (const float*)d_in[16];
  const float* w_e1     = (const float*)d_in[17];
  const float* b_e1     = (const float*)d_in[18];
  const float* w_e2     = (const float*)d_in[19];
  const float* b_e2     = (const float*)d_in[20];
  const float* ln_f_g   = (const float*)d_in[21];
  const float* ln_f_b   = (const float*)d_in[22];
  const float* w_head   = (const float*)d_in[23];
  const float* b_head   = (const float*)d_in[24];
  float* out = (float*)d_out;

  // workspace layout (floats). total ~22.3M floats ~= 90 MB
  float* ws     = (float*)d_ws;
  float* pm     = ws;                           // TP*DD
  float* h      = pm     + (size_t)TP*DD;       // TT*DD
  float* xln    = h      + (size_t)TT*DD;       // TT*DD
  float* qkvb   = xln    + (size_t)TT*DD;       // TT*QKVN
  float* attnb  = qkvb   + (size_t)TT*QKVN;     // TT*DD
  float* hid    = attnb  + (size_t)TT*DD;       // MAXA*HID
  float* moeout = hid    + (size_t)MAXA*HID;    // TT*2*DD
  float* clsln  = moeout + (size_t)TT*2*DD;     // 8*DD
  float* g01    = clsln  + (size_t)8*DD;        // TT*2
  float* gate_l = g01    + (size_t)TT*2;        // MAXA
  int*   e01    = (int*)(gate_l + MAXA);        // TT*2
  int*   cnt    = e01    + TT*2;                // 8
  int*   cnt2   = cnt    + 8;                   // 8  (contiguous with cnt for zero_k)
  int*   offs   = cnt2   + 8;                   // 9
  int*   tok_l  = offs   + 9;                   // MAXA
  int*   slot_l = tok_l  + MAXA;                // MAXA
  (void)in_sizes; (void)n_in; (void)out_size; (void)ws_size;

  // patch embedding
  patchify_k<<<(TP*DD + 255)/256, 256, 0, stream>>>(x, pm);
  gemm_k<<<dim3(DD/64, (TP+63)/64), 256, 0, stream>>>(pm, w_patch, b_patch, nullptr, xln,
                                                      TP, DD, DD, F_BIAS);
  assemble_k<<<(TT*DD + 255)/256, 256, 0, stream>>>(xln, cls_tok, pos_emb, h);

  const int MT = (TT + 63) / 64;   // 25 row tiles
  for (int i = 0; i < 4; i++) {
    // attention
    ln_k<<<TT, 256, 0, stream>>>(h, DD, ln1_g + (size_t)i*DD, ln1_b + (size_t)i*DD, xln, TT);
    gemm_k<<<dim3(QKVN/64, MT), 256, 0, stream>>>(xln, w_qkv + (size_t)i*DD*QKVN, nullptr,
                                                  nullptr, qkvb, TT, QKVN, DD, 0);
    attn_k<<<dim3(NTOK, BB*NHEAD), 256, 0, stream>>>(qkvb, attnb);
    gemm_k<<<dim3(DD/64, MT), 256, 0, stream>>>(attnb, w_proj + (size_t)i*DD*DD,
                                                b_proj + (size_t)i*DD, h, h,
                                                TT, DD, DD, F_BIAS | F_RESID);
    // mlp / moe
    ln_k<<<TT, 256, 0, stream>>>(h, DD, ln2_g + (size_t)i*DD, ln2_b + (size_t)i*DD, xln, TT);
    int j = i >> 1;
    if ((i & 1) == 0) {
      gemm_k<<<dim3(HID/64, MT), 256, 0, stream>>>(xln, w_fc1 + (size_t)j*DD*HID,
                                                   b_fc1 + (size_t)j*HID, nullptr, hid,
                                                   TT, HID, DD, F_BIAS | F_GELU);
      gemm_k<<<dim3(DD/64, MT), 256, 0, stream>>>(hid, w_fc2 + (size_t)j*HID*DD,
                                                  b_fc2 + (size_t)j*DD, h, h,
                                                  TT, DD, HID, F_BIAS | F_RESID);
    } else {
      zero_k<<<1, 64, 0, stream>>>(cnt);
      gate_k<<<(TT+63)/64, 64, 0, stream>>>(xln, w_gate + (size_t)j*DD*NEXP, e01, g01, cnt);
      offs_k<<<1, 32, 0, stream>>>(cnt, offs);
      scatter_k<<<(TT+63)/64, 64, 0, stream>>>(e01, g01, offs, cnt2, tok_l, gate_l, slot_l);
      moe_gemm1_k<<<dim3(HID/64, NAT), 256, 0, stream>>>(xln, w_e1 + (size_t)j*NEXP*DD*HID,
                                                         b_e1 + (size_t)j*NEXP*HID,
                                                         offs, cnt, tok_l, hid);
      moe_gemm2_k<<<dim3(DD/64, NAT), 256, 0, stream>>>(hid, w_e2 + (size_t)j*NEXP*HID*DD,
                                                        b_e2 + (size_t)j*NEXP*DD,
                                                        offs, cnt, tok_l, slot_l, gate_l, moeout);
      combine_k<<<(TT*DD + 255)/256, 256, 0, stream>>>(moeout, h);
    }
  }

  // final LN on cls rows + head
  ln_k<<<8, 256, 0, stream>>>(h, (size_t)NTOK*DD, ln_f_g, ln_f_b, clsln, 8);
  head_k<<<(BB*NCLS + 255)/256, 256, 0, stream>>>(clsln, w_head, b_head, out);
}

// Round 2
// 2603.762 us; speedup vs baseline: 1.7338x; 1.7338x over previous
//
#include <hip/hip_runtime.h>
#include <math.h>

// ---------------- problem constants ----------------
#define DD 768
#define NHEAD 12
#define HDIM 64
#define NTOK 197
#define BB 8
#define TT (BB*NTOK)          // 1576 tokens
#define NPATCH 196
#define TP (BB*NPATCH)        // 1568 patch rows
#define HID 3072
#define NEXP 8
#define NCLS 1000
#define QKVN (3*DD)           // 2304
#define MAXA 4224             // 33*128 padded MoE capacity (2*TT + 8*127 = 4168)
#define NAT 33                // MoE row tiles of 128

// epilogue flags
#define F_BIAS    1
#define F_GELU    2
#define F_RESID   4
#define F_OUTBF   8
#define F_MOE     16
#define F_GATHER  32
#define F_SCATTER 64

typedef __bf16 bf16_t;
typedef __attribute__((ext_vector_type(8))) __bf16 bf16x8;
typedef __attribute__((ext_vector_type(4))) float f32x4;

__device__ __forceinline__ float gelu_f(float x) {
  return 0.5f * x * (1.0f + erff(x * 0.70710678118654752f));
}

// ---------------- transpose+cast: src fp32 [K][N] -> dst bf16 [N][K] ----------------
// K,N multiples of 32. blockIdx.z = matrix index (stride K*N both sides).
__global__ void tcast_k(const float* __restrict__ src, bf16_t* __restrict__ dst,
                        int K, int N) {
  src += (size_t)blockIdx.z * K * N;
  dst += (size_t)blockIdx.z * K * N;
  __shared__ float t[32][33];
  int n0 = blockIdx.x * 32, k0 = blockIdx.y * 32;
  int tx = threadIdx.x, ty = threadIdx.y;      // 32 x 8
  #pragma unroll
  for (int i = 0; i < 4; i++)
    t[ty + i*8][tx] = src[(size_t)(k0 + ty + i*8) * N + n0 + tx];
  __syncthreads();
  #pragma unroll
  for (int i = 0; i < 4; i++)
    dst[(size_t)(n0 + ty + i*8) * K + k0 + tx] = (bf16_t)t[tx][ty + i*8];
}

// ---------------- patchify: x[B,3,224,224] -> pm_bf[1568,768] bf16 ----------------
__global__ void patchify_k(const float* __restrict__ x, bf16_t* __restrict__ pm) {
  int idx = blockIdx.x * 256 + threadIdx.x;
  if (idx >= TP * DD) return;
  int cidx = idx % DD;
  int row  = idx / DD;
  int b = row / NPATCH, p = row % NPATCH;
  int c = cidx >> 8;
  int rem = cidx & 255;
  int i = rem >> 4, j = rem & 15;
  int gy = p / 14, gx = p % 14;
  pm[idx] = (bf16_t)x[((size_t)(b*3 + c)*224 + gy*16 + i)*224 + gx*16 + j];
}

// ---------------- assemble h (fp32): cls+pos / tok+pos ----------------
__global__ void assemble_k(const float* __restrict__ tok, const float* __restrict__ cls,
                           const float* __restrict__ pos, float* __restrict__ h) {
  int idx = blockIdx.x * 256 + threadIdx.x;
  if (idx >= TT * DD) return;
  int c = idx % DD;
  int row = idx / DD;
  int b = row / NTOK, n = row % NTOK;
  float v;
  if (n == 0) v = cls[c] + pos[c];
  else        v = tok[((size_t)(b*NPATCH + n - 1))*DD + c] + pos[(size_t)n*DD + c];
  h[idx] = v;
}

// ---------------- layernorm (dual fp32 + optional bf16 out) ----------------
__global__ void ln_k(const float* __restrict__ in, size_t in_stride,
                     const float* __restrict__ g, const float* __restrict__ bta,
                     float* __restrict__ out, bf16_t* __restrict__ out_bf, int nrows) {
  int r = blockIdx.x;
  if (r >= nrows) return;
  const float* xr = in + (size_t)r * in_stride;
  __shared__ float red[256];
  int tid = threadIdx.x;
  float v0 = xr[tid], v1 = xr[tid+256], v2 = xr[tid+512];
  red[tid] = v0 + v1 + v2; __syncthreads();
  for (int st = 128; st > 0; st >>= 1) { if (tid < st) red[tid] += red[tid+st]; __syncthreads(); }
  float mean = red[0] * (1.0f/768.0f); __syncthreads();
  float d0 = v0-mean, d1 = v1-mean, d2 = v2-mean;
  red[tid] = d0*d0 + d1*d1 + d2*d2; __syncthreads();
  for (int st = 128; st > 0; st >>= 1) { if (tid < st) red[tid] += red[tid+st]; __syncthreads(); }
  float rstd = rsqrtf(red[0] * (1.0f/768.0f) + 1e-5f);
  float o0 = d0*rstd*g[tid]     + bta[tid];
  float o1 = d1*rstd*g[tid+256] + bta[tid+256];
  float o2 = d2*rstd*g[tid+512] + bta[tid+512];
  float* o = out + (size_t)r * DD;
  o[tid] = o0; o[tid+256] = o1; o[tid+512] = o2;
  if (out_bf) {
    bf16_t* ob = out_bf + (size_t)r * DD;
    ob[tid] = (bf16_t)o0; ob[tid+256] = (bf16_t)o1; ob[tid+512] = (bf16_t)o2;
  }
}

// ---------------- MFMA GEMM: C[M,N] = epi(A[M,K] @ B[K,N]) ----------------
// A: bf16 [M][K] row-major (optionally gathered rows via tok_l)
// Bt: bf16 [N][K] (weights pre-transposed); MoE: [e][N][K]
// 128x128 tile, BK=32, 256 threads (4 waves), wave computes 64x64 via 4x4 mfma 16x16x32.
// LDS layout: 8 blocks of 1024B; block mi holds rows [16mi,16mi+16) as 64 chunks of
// 16B ordered (kq*16 + r) so both staging writes and fragment reads are base+lane*16.
__global__ __launch_bounds__(256) void mgemm_k(
    const bf16_t* __restrict__ A, const bf16_t* __restrict__ Bt,
    const float* __restrict__ bias, const float* __restrict__ resid,
    float* __restrict__ Cf, bf16_t* __restrict__ Cb,
    int M, int N, int K, int flags,
    const int* __restrict__ offs, const int* __restrict__ cnt,
    const int* __restrict__ tok_l, const int* __restrict__ slot_l,
    const float* __restrict__ gate_l, float* __restrict__ scat_out) {
  int row0 = blockIdx.y << 7;
  int col0 = blockIdx.x << 7;
  int vend = M;
  const bf16_t* bt = Bt;
  const float* bs = bias;
  if (flags & F_MOE) {
    int total = offs[NEXP];
    if (row0 >= total) return;
    int e = 0;
    #pragma unroll
    for (int q = 1; q < NEXP; q++) if (row0 >= offs[q]) e = q;
    vend = offs[e] + cnt[e];
    bt = Bt + (size_t)e * N * K;
    bs = bias ? bias + (size_t)e * N : bias;
  }
  int tid = threadIdx.x, wave = tid >> 6, lane = tid & 63;
  int r16 = lane & 15, kq = lane >> 4;
  int kq8 = kq << 3;
  __shared__ bf16_t As[128*32];
  __shared__ bf16_t Bs[128*32];
  const bf16_t* aptr[2];
  const bf16_t* bptr[2];
  #pragma unroll
  for (int s = 0; s < 2; s++) {
    int blk = wave*2 + s;
    int rl = (blk << 4) + r16;
    int gr = row0 + rl;
    if (flags & F_GATHER) {
      int t = (gr < vend) ? tok_l[gr] : 0;
      aptr[s] = A + (size_t)t * K;
    } else {
      int cr = gr; if (cr > vend - 1) cr = vend - 1;
      aptr[s] = A + (size_t)cr * K;
    }
    bptr[s] = bt + (size_t)(col0 + rl) * K;
  }
  int woff = (wave*2) * 512 + lane * 8;
  int mi0 = (wave >> 1) * 4, ni0 = (wave & 1) * 4;
  f32x4 acc[4][4];
  #pragma unroll
  for (int i = 0; i < 4; i++)
    #pragma unroll
    for (int j = 0; j < 4; j++)
      acc[i][j] = (f32x4){0.f, 0.f, 0.f, 0.f};

  for (int k0 = 0; k0 < K; k0 += 32) {
    uint4 a0 = *(const uint4*)(aptr[0] + k0 + kq8);
    uint4 a1 = *(const uint4*)(aptr[1] + k0 + kq8);
    uint4 b0 = *(const uint4*)(bptr[0] + k0 + kq8);
    uint4 b1 = *(const uint4*)(bptr[1] + k0 + kq8);
    __syncthreads();
    *(uint4*)&As[woff]       = a0;
    *(uint4*)&As[woff + 512] = a1;
    *(uint4*)&Bs[woff]       = b0;
    *(uint4*)&Bs[woff + 512] = b1;
    __syncthreads();
    bf16x8 af[4], bfr[4];
    #pragma unroll
    for (int i = 0; i < 4; i++) af[i]  = *(const bf16x8*)&As[(mi0+i)*512 + lane*8];
    #pragma unroll
    for (int j = 0; j < 4; j++) bfr[j] = *(const bf16x8*)&Bs[(ni0+j)*512 + lane*8];
    #pragma unroll
    for (int i = 0; i < 4; i++)
      #pragma unroll
      for (int j = 0; j < 4; j++)
        acc[i][j] = __builtin_amdgcn_mfma_f32_16x16x32_bf16(af[i], bfr[j], acc[i][j], 0, 0, 0);
  }

  int rq = kq << 2;
  #pragma unroll
  for (int i = 0; i < 4; i++) {
    #pragma unroll
    for (int p = 0; p < 4; p++) {
      int rr = row0 + ((mi0 + i) << 4) + rq + p;
      if (rr >= vend) continue;
      int t = 0, sl = 0; float gv = 0.f;
      if (flags & F_SCATTER) { t = tok_l[rr]; sl = slot_l[rr]; gv = gate_l[rr]; }
      #pragma unroll
      for (int j = 0; j < 4; j++) {
        int cc = col0 + ((ni0 + j) << 4) + r16;
        float v = acc[i][j][p];
        if (flags & F_BIAS) v += bs[cc];
        if (flags & F_GELU) v = gelu_f(v);
        if (flags & F_SCATTER) {
          scat_out[((size_t)t*2 + sl)*N + cc] = gv * v;
        } else if (flags & F_RESID) {
          Cf[(size_t)rr*N + cc] = v + resid[(size_t)rr*N + cc];
        } else if (flags & F_OUTBF) {
          Cb[(size_t)rr*N + cc] = (bf16_t)v;
        } else {
          Cf[(size_t)rr*N + cc] = v;
        }
      }
    }
  }
}

// ---------------- attention: one block per (query, b*head), fp32 qkv, bf16 out ----------------
__global__ void attn_k(const float* __restrict__ qkv, bf16_t* __restrict__ out) {
  int n  = blockIdx.x;
  int bh = blockIdx.y;
  int b = bh / NHEAD, hh = bh % NHEAD;
  const float* base = qkv + (size_t)b * NTOK * QKVN;
  __shared__ float q[HDIM];
  __shared__ float sc[NTOK];
  __shared__ float red[256];
  int tid = threadIdx.x;
  if (tid < HDIM) q[tid] = base[(size_t)n*QKVN + hh*HDIM + tid];
  __syncthreads();
  for (int jj = tid; jj < NTOK; jj += 256) {
    const float* kr = base + (size_t)jj*QKVN + DD + hh*HDIM;
    float s = 0.0f;
    #pragma unroll
    for (int d = 0; d < HDIM; d++) s += q[d] * kr[d];
    sc[jj] = s * 0.125f;
  }
  __syncthreads();
  float m = -1e30f;
  for (int jj = tid; jj < NTOK; jj += 256) m = fmaxf(m, sc[jj]);
  red[tid] = m; __syncthreads();
  for (int st = 128; st > 0; st >>= 1) { if (tid < st) red[tid] = fmaxf(red[tid], red[tid+st]); __syncthreads(); }
  m = red[0]; __syncthreads();
  float sum = 0.0f;
  for (int jj = tid; jj < NTOK; jj += 256) { float ev = expf(sc[jj] - m); sc[jj] = ev; sum += ev; }
  red[tid] = sum; __syncthreads();
  for (int st = 128; st > 0; st >>= 1) { if (tid < st) red[tid] += red[tid+st]; __syncthreads(); }
  float inv = 1.0f / red[0];
  __syncthreads();
  int d = tid & 63, j4 = tid >> 6;
  float acc = 0.0f;
  for (int jj = j4; jj < NTOK; jj += 4)
    acc += sc[jj] * base[(size_t)jj*QKVN + 2*DD + hh*HDIM + d];
  red[tid] = acc; __syncthreads();
  if (tid < 64) {
    float o = (red[tid] + red[tid+64] + red[tid+128] + red[tid+192]) * inv;
    out[((size_t)b*NTOK + n)*DD + hh*HDIM + d] = (bf16_t)o;
  }
}

// ---------------- MoE routing (fp32 gate path) ----------------
__global__ void zero_k(int* __restrict__ cnt) {
  if (threadIdx.x < 16) cnt[threadIdx.x] = 0;
}

__global__ void gate_k(const float* __restrict__ xln, const float* __restrict__ wg,
                       int* __restrict__ e01, float* __restrict__ g01, int* __restrict__ cnt) {
  int t = blockIdx.x * 64 + threadIdx.x;
  if (t >= TT) return;
  float lg[NEXP] = {};
  const float* xr = xln + (size_t)t * DD;
  for (int k = 0; k < DD; k++) {
    float xv = xr[k];
    const float* wr = wg + (size_t)k * NEXP;
    #pragma unroll
    for (int e = 0; e < NEXP; e++) lg[e] += xv * wr[e];
  }
  int e0 = 0; float v0 = lg[0];
  #pragma unroll
  for (int e = 1; e < NEXP; e++) if (lg[e] > v0) { v0 = lg[e]; e0 = e; }
  int e1 = -1; float v1 = -1e30f;
  #pragma unroll
  for (int e = 0; e < NEXP; e++) if (e != e0 && lg[e] > v1) { v1 = lg[e]; e1 = e; }
  float g0 = 1.0f / (1.0f + expf(v1 - v0));
  float g1 = 1.0f - g0;
  e01[t*2]   = e0; e01[t*2+1] = e1;
  g01[t*2]   = g0; g01[t*2+1] = g1;
  atomicAdd(&cnt[e0], 1);
  atomicAdd(&cnt[e1], 1);
}

__global__ void offs_k(const int* __restrict__ cnt, int* __restrict__ offs) {
  if (threadIdx.x == 0 && blockIdx.x == 0) {
    int acc = 0;
    for (int e = 0; e < NEXP; e++) {
      offs[e] = acc;
      acc += ((cnt[e] + 127) >> 7) << 7;   // pad segments to 128 rows
    }
    offs[NEXP] = acc;
  }
}

__global__ void scatter_k(const int* __restrict__ e01, const float* __restrict__ g01,
                          const int* __restrict__ offs, int* __restrict__ cnt2,
                          int* __restrict__ tok_l, float* __restrict__ gate_l,
                          int* __restrict__ slot_l) {
  int t = blockIdx.x * 64 + threadIdx.x;
  if (t >= TT) return;
  #pragma unroll
  for (int s = 0; s < 2; s++) {
    int e = e01[t*2+s];
    int pos = atomicAdd(&cnt2[e], 1);
    int a = offs[e] + pos;
    tok_l[a] = t;
    gate_l[a] = g01[t*2+s];
    slot_l[a] = s;
  }
}

__global__ void combine_k(const float* __restrict__ moe_out, float* __restrict__ h) {
  int idx = blockIdx.x * 256 + threadIdx.x;
  if (idx >= TT * DD) return;
  int c = idx % DD;
  int row = idx / DD;
  h[idx] += moe_out[((size_t)row*2)*DD + c] + moe_out[((size_t)row*2 + 1)*DD + c];
}

// ---------------- head (fp32, small) ----------------
__global__ void head_k(const float* __restrict__ clsln, const float* __restrict__ w_head,
                       const float* __restrict__ b_head, float* __restrict__ out) {
  int id = blockIdx.x * 256 + threadIdx.x;
  if (id >= BB * NCLS) return;
  int b = id / NCLS, c = id % NCLS;
  float acc = b_head[c];
  const float* xr = clsln + (size_t)b * DD;
  for (int k = 0; k < DD; k++) acc += xr[k] * w_head[(size_t)k*NCLS + c];
  out[id] = acc;
}

// ---------------- host ----------------
extern "C" void kernel_launch(void* const* d_in, const int* in_sizes, int n_in,
                              void* d_out, int out_size, void* d_ws, size_t ws_size,
                              hipStream_t stream) {
  const float* x        = (const float*)d_in[0];
  const float* w_patch  = (const float*)d_in[1];
  const float* b_patch  = (const float*)d_in[2];
  const float* cls_tok  = (const float*)d_in[3];
  const float* pos_emb  = (const float*)d_in[4];
  const float* ln1_g    = (const float*)d_in[5];
  const float* ln1_b    = (const float*)d_in[6];
  const float* w_qkv    = (const float*)d_in[7];
  const float* w_proj   = (const float*)d_in[8];
  const float* b_proj   = (const float*)d_in[9];
  const float* ln2_g    = (const float*)d_in[10];
  const float* ln2_b    = (const float*)d_in[11];
  const float* w_fc1    = (const float*)d_in[12];
  const float* b_fc1    = (const float*)d_in[13];
  const float* w_fc2    = (const float*)d_in[14];
  const float* b_fc2    = (const float*)d_in[15];
  const float* w_gate   = (const float*)d_in[16];
  const float* w_e1     = (const float*)d_in[17];
  const float* b_e1     = (const float*)d_in[18];
  const float* w_e2     = (const float*)d_in[19];
  const float* b_e2     = (const float*)d_in[20];
  const float* ln_f_g   = (const float*)d_in[21];
  const float* ln_f_b   = (const float*)d_in[22];
  const float* w_head   = (const float*)d_in[23];
  const float* b_head   = (const float*)d_in[24];
  float* out = (float*)d_out;
  (void)in_sizes; (void)n_in; (void)out_size; (void)ws_size;

  // ---- workspace layout ----
  float* fp = (float*)d_ws;
  float* h      = fp;                          fp += (size_t)TT*DD;
  float* xln    = fp;                          fp += (size_t)TT*DD;     // also patch-gemm out
  float* qkvb   = fp;                          fp += (size_t)TT*QKVN;
  float* moeout = fp;                          fp += (size_t)TT*2*DD;
  float* clsln  = fp;                          fp += (size_t)8*DD;
  float* g01    = fp;                          fp += (size_t)TT*2;
  float* gate_l = fp;                          fp += (size_t)MAXA;
  int* ip = (int*)fp;
  int* e01    = ip;                            ip += TT*2;
  int* cnt    = ip;                            ip += 8;
  int* cnt2   = ip;                            ip += 8;
  int* offs   = ip;                            ip += 16;
  int* tok_l  = ip;                            ip += MAXA;
  int* slot_l = ip;                            ip += MAXA;
  bf16_t* bp = (bf16_t*)ip;
  bf16_t* pm_bf   = bp;                        bp += (size_t)TP*DD;
  bf16_t* xln_bf  = bp;                        bp += (size_t)TT*DD;
  bf16_t* attnb   = bp;                        bp += (size_t)TT*DD;
  bf16_t* hid     = bp;                        bp += (size_t)MAXA*HID;
  bf16_t* wT_patch= bp;                        bp += (size_t)DD*DD;
  bf16_t* wT_qkv  = bp;                        bp += (size_t)DD*QKVN;
  bf16_t* wT_proj = bp;                        bp += (size_t)DD*DD;
  bf16_t* wT_big  = bp;                        bp += (size_t)NEXP*DD*HID;  // reused

  // ---- patch embedding ----
  tcast_k<<<dim3(DD/32, DD/32, 1), dim3(32,8), 0, stream>>>(w_patch, wT_patch, DD, DD);
  patchify_k<<<(TP*DD + 255)/256, 256, 0, stream>>>(x, pm_bf);
  mgemm_k<<<dim3(DD/128, (TP+127)/128), 256, 0, stream>>>(
      pm_bf, wT_patch, b_patch, nullptr, xln, nullptr, TP, DD, DD, F_BIAS,
      nullptr, nullptr, nullptr, nullptr, nullptr, nullptr);
  assemble_k<<<(TT*DD + 255)/256, 256, 0, stream>>>(xln, cls_tok, pos_emb, h);

  const int MT = (TT + 127) / 128;   // 13 row tiles
  for (int i = 0; i < 4; i++) {
    int j = i >> 1;
    // attention
    tcast_k<<<dim3(QKVN/32, DD/32, 1), dim3(32,8), 0, stream>>>(
        w_qkv + (size_t)i*DD*QKVN, wT_qkv, DD, QKVN);
    tcast_k<<<dim3(DD/32, DD/32, 1), dim3(32,8), 0, stream>>>(
        w_proj + (size_t)i*DD*DD, wT_proj, DD, DD);
    ln_k<<<TT, 256, 0, stream>>>(h, DD, ln1_g + (size_t)i*DD, ln1_b + (size_t)i*DD,
                                 xln, xln_bf, TT);
    mgemm_k<<<dim3(QKVN/128, MT), 256, 0, stream>>>(
        xln_bf, wT_qkv, nullptr, nullptr, qkvb, nullptr, TT, QKVN, DD, 0,
        nullptr, nullptr, nullptr, nullptr, nullptr, nullptr);
    attn_k<<<dim3(NTOK, BB*NHEAD), 256, 0, stream>>>(qkvb, attnb);
    mgemm_k<<<dim3(DD/128, MT), 256, 0, stream>>>(
        attnb, wT_proj, b_proj + (size_t)i*DD, h, h, nullptr, TT, DD, DD,
        F_BIAS | F_RESID, nullptr, nullptr, nullptr, nullptr, nullptr, nullptr);
    // mlp / moe
    ln_k<<<TT, 256, 0, stream>>>(h, DD, ln2_g + (size_t)i*DD, ln2_b + (size_t)i*DD,
                                 xln, xln_bf, TT);
    if ((i & 1) == 0) {
      tcast_k<<<dim3(HID/32, DD/32, 1), dim3(32,8), 0, stream>>>(
          w_fc1 + (size_t)j*DD*HID, wT_big, DD, HID);
      mgemm_k<<<dim3(HID/128, MT), 256, 0, stream>>>(
          xln_bf, wT_big, b_fc1 + (size_t)j*HID, nullptr, nullptr, hid,
          TT, HID, DD, F_BIAS | F_GELU | F_OUTBF,
          nullptr, nullptr, nullptr, nullptr, nullptr, nullptr);
      tcast_k<<<dim3(DD/32, HID/32, 1), dim3(32,8), 0, stream>>>(
          w_fc2 + (size_t)j*HID*DD, wT_big, HID, DD);
      mgemm_k<<<dim3(DD/128, MT), 256, 0, stream>>>(
          hid, wT_big, b_fc2 + (size_t)j*DD, h, h, nullptr, TT, DD, HID,
          F_BIAS | F_RESID, nullptr, nullptr, nullptr, nullptr, nullptr, nullptr);
    } else {
      zero_k<<<1, 64, 0, stream>>>(cnt);
      gate_k<<<(TT+63)/64, 64, 0, stream>>>(xln, w_gate + (size_t)j*DD*NEXP, e01, g01, cnt);
      offs_k<<<1, 32, 0, stream>>>(cnt, offs);
      scatter_k<<<(TT+63)/64, 64, 0, stream>>>(e01, g01, offs, cnt2, tok_l, gate_l, slot_l);
      tcast_k<<<dim3(HID/32, DD/32, NEXP), dim3(32,8), 0, stream>>>(
          w_e1 + (size_t)j*NEXP*DD*HID, wT_big, DD, HID);
      mgemm_k<<<dim3(HID/128, NAT), 256, 0, stream>>>(
          xln_bf, wT_big, b_e1 + (size_t)j*NEXP*HID, nullptr, nullptr, hid,
          0, HID, DD, F_MOE | F_GATHER | F_BIAS | F_GELU | F_OUTBF,
          offs, cnt, tok_l, nullptr, nullptr, nullptr);
      tcast_k<<<dim3(DD/32, HID/32, NEXP), dim3(32,8), 0, stream>>>(
          w_e2 + (size_t)j*NEXP*HID*DD, wT_big, HID, DD);
      mgemm_k<<<dim3(DD/128, NAT), 256, 0, stream>>>(
          hid, wT_big, b_e2 + (size_t)j*NEXP*DD, nullptr, nullptr, nullptr,
          0, DD, HID, F_MOE | F_SCATTER | F_BIAS,
          offs, cnt, tok_l, slot_l, gate_l, moeout);
      combine_k<<<(TT*DD + 255)/256, 256, 0, stream>>>(moeout, h);
    }
  }

  ln_k<<<8, 256, 0, stream>>>(h, (size_t)NTOK*DD, ln_f_g, ln_f_b, clsln, nullptr, 8);
  head_k<<<(BB*NCLS + 255)/256, 256, 0, stream>>>(clsln, w_head, b_head, out);
}

// Round 3
// 1869.126 us; speedup vs baseline: 2.4153x; 1.3930x over previous
//
#include <hip/hip_runtime.h>
#include <math.h>

// ---------------- problem constants ----------------
#define DD 768
#define NHEAD 12
#define HDIM 64
#define NTOK 197
#define BB 8
#define TT (BB*NTOK)          // 1576 tokens
#define NPATCH 196
#define TP (BB*NPATCH)        // 1568 patch rows
#define HID 3072
#define NEXP 8
#define NCLS 1000
#define QKVN (3*DD)           // 2304
#define MAXA 4224             // 33*128 padded MoE capacity (2*TT + 8*127 = 4168)
#define NAT 33                // MoE row tiles of 128
#define NCH 7                 // attention: 7 chunks of 32 cols (224 >= 197)

// epilogue flags
#define F_BIAS    1
#define F_GELU    2
#define F_RESID   4
#define F_OUTBF   8
#define F_MOE     16
#define F_GATHER  32
#define F_SCATTER 64

typedef __bf16 bf16_t;
typedef __attribute__((ext_vector_type(8))) __bf16 bf16x8;
typedef __attribute__((ext_vector_type(4))) float f32x4;

__device__ __forceinline__ float gelu_f(float x) {
  return 0.5f * x * (1.0f + erff(x * 0.70710678118654752f));
}

// ---------------- transpose+cast: src fp32 [K][N] -> dst bf16 [N][K] ----------------
__global__ void tcast_k(const float* __restrict__ src, bf16_t* __restrict__ dst,
                        int K, int N) {
  src += (size_t)blockIdx.z * K * N;
  dst += (size_t)blockIdx.z * K * N;
  __shared__ float t[32][33];
  int n0 = blockIdx.x * 32, k0 = blockIdx.y * 32;
  int tx = threadIdx.x, ty = threadIdx.y;      // 32 x 8
  #pragma unroll
  for (int i = 0; i < 4; i++)
    t[ty + i*8][tx] = src[(size_t)(k0 + ty + i*8) * N + n0 + tx];
  __syncthreads();
  #pragma unroll
  for (int i = 0; i < 4; i++)
    dst[(size_t)(n0 + ty + i*8) * K + k0 + tx] = (bf16_t)t[tx][ty + i*8];
}

// ---------------- patchify: x[B,3,224,224] -> pm_bf[1568,768] bf16 ----------------
__global__ void patchify_k(const float* __restrict__ x, bf16_t* __restrict__ pm) {
  int idx = blockIdx.x * 256 + threadIdx.x;
  if (idx >= TP * DD) return;
  int cidx = idx % DD;
  int row  = idx / DD;
  int b = row / NPATCH, p = row % NPATCH;
  int c = cidx >> 8;
  int rem = cidx & 255;
  int i = rem >> 4, j = rem & 15;
  int gy = p / 14, gx = p % 14;
  pm[idx] = (bf16_t)x[((size_t)(b*3 + c)*224 + gy*16 + i)*224 + gx*16 + j];
}

// ---------------- assemble h (fp32): cls+pos / tok+pos ----------------
__global__ void assemble_k(const float* __restrict__ tok, const float* __restrict__ cls,
                           const float* __restrict__ pos, float* __restrict__ h) {
  int idx = blockIdx.x * 256 + threadIdx.x;
  if (idx >= TT * DD) return;
  int c = idx % DD;
  int row = idx / DD;
  int b = row / NTOK, n = row % NTOK;
  float v;
  if (n == 0) v = cls[c] + pos[c];
  else        v = tok[((size_t)(b*NPATCH + n - 1))*DD + c] + pos[(size_t)n*DD + c];
  h[idx] = v;
}

// ---------------- layernorm (dual fp32 + optional bf16 out) ----------------
__global__ void ln_k(const float* __restrict__ in, size_t in_stride,
                     const float* __restrict__ g, const float* __restrict__ bta,
                     float* __restrict__ out, bf16_t* __restrict__ out_bf, int nrows) {
  int r = blockIdx.x;
  if (r >= nrows) return;
  const float* xr = in + (size_t)r * in_stride;
  __shared__ float red[256];
  int tid = threadIdx.x;
  float v0 = xr[tid], v1 = xr[tid+256], v2 = xr[tid+512];
  red[tid] = v0 + v1 + v2; __syncthreads();
  for (int st = 128; st > 0; st >>= 1) { if (tid < st) red[tid] += red[tid+st]; __syncthreads(); }
  float mean = red[0] * (1.0f/768.0f); __syncthreads();
  float d0 = v0-mean, d1 = v1-mean, d2 = v2-mean;
  red[tid] = d0*d0 + d1*d1 + d2*d2; __syncthreads();
  for (int st = 128; st > 0; st >>= 1) { if (tid < st) red[tid] += red[tid+st]; __syncthreads(); }
  float rstd = rsqrtf(red[0] * (1.0f/768.0f) + 1e-5f);
  float o0 = d0*rstd*g[tid]     + bta[tid];
  float o1 = d1*rstd*g[tid+256] + bta[tid+256];
  float o2 = d2*rstd*g[tid+512] + bta[tid+512];
  float* o = out + (size_t)r * DD;
  o[tid] = o0; o[tid+256] = o1; o[tid+512] = o2;
  if (out_bf) {
    bf16_t* ob = out_bf + (size_t)r * DD;
    ob[tid] = (bf16_t)o0; ob[tid+256] = (bf16_t)o1; ob[tid+512] = (bf16_t)o2;
  }
}

// ---------------- MFMA GEMM (as round 2) ----------------
__global__ __launch_bounds__(256) void mgemm_k(
    const bf16_t* __restrict__ A, const bf16_t* __restrict__ Bt,
    const float* __restrict__ bias, const float* __restrict__ resid,
    float* __restrict__ Cf, bf16_t* __restrict__ Cb,
    int M, int N, int K, int flags,
    const int* __restrict__ offs, const int* __restrict__ cnt,
    const int* __restrict__ tok_l, const int* __restrict__ slot_l,
    const float* __restrict__ gate_l, float* __restrict__ scat_out) {
  int row0 = blockIdx.y << 7;
  int col0 = blockIdx.x << 7;
  int vend = M;
  const bf16_t* bt = Bt;
  const float* bs = bias;
  if (flags & F_MOE) {
    int total = offs[NEXP];
    if (row0 >= total) return;
    int e = 0;
    #pragma unroll
    for (int q = 1; q < NEXP; q++) if (row0 >= offs[q]) e = q;
    vend = offs[e] + cnt[e];
    bt = Bt + (size_t)e * N * K;
    bs = bias ? bias + (size_t)e * N : bias;
  }
  int tid = threadIdx.x, wave = tid >> 6, lane = tid & 63;
  int r16 = lane & 15, kq = lane >> 4;
  int kq8 = kq << 3;
  __shared__ bf16_t As[128*32];
  __shared__ bf16_t Bs[128*32];
  const bf16_t* aptr[2];
  const bf16_t* bptr[2];
  #pragma unroll
  for (int s = 0; s < 2; s++) {
    int blk = wave*2 + s;
    int rl = (blk << 4) + r16;
    int gr = row0 + rl;
    if (flags & F_GATHER) {
      int t = (gr < vend) ? tok_l[gr] : 0;
      aptr[s] = A + (size_t)t * K;
    } else {
      int cr = gr; if (cr > vend - 1) cr = vend - 1;
      aptr[s] = A + (size_t)cr * K;
    }
    bptr[s] = bt + (size_t)(col0 + rl) * K;
  }
  int woff = (wave*2) * 512 + lane * 8;
  int mi0 = (wave >> 1) * 4, ni0 = (wave & 1) * 4;
  f32x4 acc[4][4];
  #pragma unroll
  for (int i = 0; i < 4; i++)
    #pragma unroll
    for (int j = 0; j < 4; j++)
      acc[i][j] = (f32x4){0.f, 0.f, 0.f, 0.f};

  for (int k0 = 0; k0 < K; k0 += 32) {
    uint4 a0 = *(const uint4*)(aptr[0] + k0 + kq8);
    uint4 a1 = *(const uint4*)(aptr[1] + k0 + kq8);
    uint4 b0 = *(const uint4*)(bptr[0] + k0 + kq8);
    uint4 b1 = *(const uint4*)(bptr[1] + k0 + kq8);
    __syncthreads();
    *(uint4*)&As[woff]       = a0;
    *(uint4*)&As[woff + 512] = a1;
    *(uint4*)&Bs[woff]       = b0;
    *(uint4*)&Bs[woff + 512] = b1;
    __syncthreads();
    bf16x8 af[4], bfr[4];
    #pragma unroll
    for (int i = 0; i < 4; i++) af[i]  = *(const bf16x8*)&As[(mi0+i)*512 + lane*8];
    #pragma unroll
    for (int j = 0; j < 4; j++) bfr[j] = *(const bf16x8*)&Bs[(ni0+j)*512 + lane*8];
    #pragma unroll
    for (int i = 0; i < 4; i++)
      #pragma unroll
      for (int j = 0; j < 4; j++)
        acc[i][j] = __builtin_amdgcn_mfma_f32_16x16x32_bf16(af[i], bfr[j], acc[i][j], 0, 0, 0);
  }

  int rq = kq << 2;
  #pragma unroll
  for (int i = 0; i < 4; i++) {
    #pragma unroll
    for (int p = 0; p < 4; p++) {
      int rr = row0 + ((mi0 + i) << 4) + rq + p;
      if (rr >= vend) continue;
      int t = 0, sl = 0; float gv = 0.f;
      if (flags & F_SCATTER) { t = tok_l[rr]; sl = slot_l[rr]; gv = gate_l[rr]; }
      #pragma unroll
      for (int j = 0; j < 4; j++) {
        int cc = col0 + ((ni0 + j) << 4) + r16;
        float v = acc[i][j][p];
        if (flags & F_BIAS) v += bs[cc];
        if (flags & F_GELU) v = gelu_f(v);
        if (flags & F_SCATTER) {
          scat_out[((size_t)t*2 + sl)*N + cc] = gv * v;
        } else if (flags & F_RESID) {
          Cf[(size_t)rr*N + cc] = v + resid[(size_t)rr*N + cc];
        } else if (flags & F_OUTBF) {
          Cb[(size_t)rr*N + cc] = (bf16_t)v;
        } else {
          Cf[(size_t)rr*N + cc] = v;
        }
      }
    }
  }
}

// ---------------- flash attention: block = (qtile of 64 rows) x (b*head) ----------------
// 4 waves; wave owns a 16-row MFMA m-tile. Q/K frags straight from global (bf16),
// V transposed into LDS once, P via per-wave LDS round-trip, online softmax fp32.
__global__ __launch_bounds__(256) void fattn_k(const bf16_t* __restrict__ qkv,
                                               bf16_t* __restrict__ out) {
  int qt = blockIdx.x;
  int bh = blockIdx.y;
  int b = bh / NHEAD, hh = bh % NHEAD;
  const bf16_t* base = qkv + (size_t)b * NTOK * QKVN;
  int tid = threadIdx.x, wave = tid >> 6, lane = tid & 63;
  int r16 = lane & 15, kq = lane >> 4;

  __shared__ bf16_t Vt[64 * 232];            // V^T [hd][seq], stride 232
  __shared__ bf16_t Ps[4][16 * 40];          // per-wave P scratch, stride 40

  // stage Vt = V^T (coalesced read, scalar LDS scatter; pad rows >=197 with 0)
  for (int it = 0; it < 56; it++) {
    int idx = it * 256 + tid;                // 0..14335
    int d = idx & 63, n = idx >> 6;          // n 0..223
    bf16_t bv = (bf16_t)0.f;
    if (n < NTOK) bv = base[(size_t)n * QKVN + 2*DD + hh*HDIM + d];
    Vt[d * 232 + n] = bv;
  }
  __syncthreads();

  // Q A-frags: rows q0 + wave*16 + r16 (invalid rows -> row 0, outputs skipped)
  int q0 = qt * 64;
  int qrow = q0 + wave * 16 + r16;
  int qr = (qrow < NTOK) ? qrow : 0;
  bf16x8 qf[2];
  #pragma unroll
  for (int ks = 0; ks < 2; ks++)
    qf[ks] = *(const bf16x8*)(base + (size_t)qr * QKVN + hh*HDIM + ks*32 + kq*8);

  f32x4 Oa[4];
  #pragma unroll
  for (int j = 0; j < 4; j++) Oa[j] = (f32x4){0.f,0.f,0.f,0.f};
  float mI[4], lI[4];
  #pragma unroll
  for (int p = 0; p < 4; p++) { mI[p] = -1e30f; lI[p] = 0.f; }

  const bf16_t* Kbase = base + DD + hh*HDIM;
  const bf16x8 zz = {};

  for (int c = 0; c < NCH; c++) {
    // ---- S = Q K^T for 32 cols ----
    f32x4 sc[2];
    sc[0] = (f32x4){0.f,0.f,0.f,0.f};
    sc[1] = (f32x4){0.f,0.f,0.f,0.f};
    #pragma unroll
    for (int tt = 0; tt < 2; tt++) {
      int n = c*32 + tt*16 + r16;
      bool nv = (n < NTOK);
      #pragma unroll
      for (int ks = 0; ks < 2; ks++) {
        bf16x8 kf = zz;
        if (nv) kf = *(const bf16x8*)(Kbase + (size_t)n * QKVN + ks*32 + kq*8);
        sc[tt] = __builtin_amdgcn_mfma_f32_16x16x32_bf16(qf[ks], kf, sc[tt], 0, 0, 0);
      }
    }
    // ---- scale + mask + online softmax ----
    float cm[4];
    #pragma unroll
    for (int p = 0; p < 4; p++) {
      #pragma unroll
      for (int tt = 0; tt < 2; tt++) {
        int col = c*32 + tt*16 + r16;
        float s = sc[tt][p] * 0.125f;
        sc[tt][p] = (col < NTOK) ? s : -1e30f;
      }
      cm[p] = fmaxf(sc[0][p], sc[1][p]);
    }
    #pragma unroll
    for (int off = 1; off < 16; off <<= 1)
      #pragma unroll
      for (int p = 0; p < 4; p++)
        cm[p] = fmaxf(cm[p], __shfl_xor(cm[p], off, 64));
    float al[4], cs[4];
    #pragma unroll
    for (int p = 0; p < 4; p++) {
      float mn = fmaxf(mI[p], cm[p]);
      al[p] = __expf(mI[p] - mn);
      mI[p] = mn;
      float e0 = __expf(sc[0][p] - mn);
      float e1 = __expf(sc[1][p] - mn);
      sc[0][p] = e0; sc[1][p] = e1;
      cs[p] = e0 + e1;
    }
    #pragma unroll
    for (int off = 1; off < 16; off <<= 1)
      #pragma unroll
      for (int p = 0; p < 4; p++)
        cs[p] += __shfl_xor(cs[p], off, 64);
    #pragma unroll
    for (int p = 0; p < 4; p++) lI[p] = lI[p]*al[p] + cs[p];
    #pragma unroll
    for (int j = 0; j < 4; j++)
      #pragma unroll
      for (int p = 0; p < 4; p++)
        Oa[j][p] *= al[p];
    // ---- P: C-layout -> A-layout via per-wave LDS ----
    bf16_t* pw = &Ps[wave][0];
    #pragma unroll
    for (int tt = 0; tt < 2; tt++)
      #pragma unroll
      for (int p = 0; p < 4; p++)
        pw[(kq*4+p)*40 + tt*16 + r16] = (bf16_t)sc[tt][p];
    bf16x8 pf = *(const bf16x8*)(pw + r16*40 + kq*8);
    // ---- O += P V ----
    #pragma unroll
    for (int j = 0; j < 4; j++) {
      bf16x8 vf = *(const bf16x8*)(&Vt[(j*16 + r16)*232 + c*32 + kq*8]);
      Oa[j] = __builtin_amdgcn_mfma_f32_16x16x32_bf16(pf, vf, Oa[j], 0, 0, 0);
    }
  }

  // epilogue
  #pragma unroll
  for (int p = 0; p < 4; p++) {
    int row = q0 + wave*16 + kq*4 + p;
    if (row >= NTOK) continue;
    float inv = 1.0f / lI[p];
    #pragma unroll
    for (int j = 0; j < 4; j++)
      out[((size_t)b*NTOK + row)*DD + hh*HDIM + j*16 + r16] = (bf16_t)(Oa[j][p] * inv);
  }
}

// ---------------- MoE routing (fp32 gate path) ----------------
__global__ void zero_k(int* __restrict__ cnt) {
  if (threadIdx.x < 16) cnt[threadIdx.x] = 0;
}

__global__ void gate_k(const float* __restrict__ xln, const float* __restrict__ wg,
                       int* __restrict__ e01, float* __restrict__ g01, int* __restrict__ cnt) {
  int t = blockIdx.x * 64 + threadIdx.x;
  if (t >= TT) return;
  float lg[NEXP] = {};
  const float* xr = xln + (size_t)t * DD;
  for (int k = 0; k < DD; k++) {
    float xv = xr[k];
    const float* wr = wg + (size_t)k * NEXP;
    #pragma unroll
    for (int e = 0; e < NEXP; e++) lg[e] += xv * wr[e];
  }
  int e0 = 0; float v0 = lg[0];
  #pragma unroll
  for (int e = 1; e < NEXP; e++) if (lg[e] > v0) { v0 = lg[e]; e0 = e; }
  int e1 = -1; float v1 = -1e30f;
  #pragma unroll
  for (int e = 0; e < NEXP; e++) if (e != e0 && lg[e] > v1) { v1 = lg[e]; e1 = e; }
  float g0 = 1.0f / (1.0f + expf(v1 - v0));
  float g1 = 1.0f - g0;
  e01[t*2]   = e0; e01[t*2+1] = e1;
  g01[t*2]   = g0; g01[t*2+1] = g1;
  atomicAdd(&cnt[e0], 1);
  atomicAdd(&cnt[e1], 1);
}

__global__ void offs_k(const int* __restrict__ cnt, int* __restrict__ offs) {
  if (threadIdx.x == 0 && blockIdx.x == 0) {
    int acc = 0;
    for (int e = 0; e < NEXP; e++) {
      offs[e] = acc;
      acc += ((cnt[e] + 127) >> 7) << 7;
    }
    offs[NEXP] = acc;
  }
}

__global__ void scatter_k(const int* __restrict__ e01, const float* __restrict__ g01,
                          const int* __restrict__ offs, int* __restrict__ cnt2,
                          int* __restrict__ tok_l, float* __restrict__ gate_l,
                          int* __restrict__ slot_l) {
  int t = blockIdx.x * 64 + threadIdx.x;
  if (t >= TT) return;
  #pragma unroll
  for (int s = 0; s < 2; s++) {
    int e = e01[t*2+s];
    int pos = atomicAdd(&cnt2[e], 1);
    int a = offs[e] + pos;
    tok_l[a] = t;
    gate_l[a] = g01[t*2+s];
    slot_l[a] = s;
  }
}

__global__ void combine_k(const float* __restrict__ moe_out, float* __restrict__ h) {
  int idx = blockIdx.x * 256 + threadIdx.x;
  if (idx >= TT * DD) return;
  int c = idx % DD;
  int row = idx / DD;
  h[idx] += moe_out[((size_t)row*2)*DD + c] + moe_out[((size_t)row*2 + 1)*DD + c];
}

// ---------------- head (fp32, small) ----------------
__global__ void head_k(const float* __restrict__ clsln, const float* __restrict__ w_head,
                       const float* __restrict__ b_head, float* __restrict__ out) {
  int id = blockIdx.x * 256 + threadIdx.x;
  if (id >= BB * NCLS) return;
  int b = id / NCLS, c = id % NCLS;
  float acc = b_head[c];
  const float* xr = clsln + (size_t)b * DD;
  for (int k = 0; k < DD; k++) acc += xr[k] * w_head[(size_t)k*NCLS + c];
  out[id] = acc;
}

// ---------------- host ----------------
extern "C" void kernel_launch(void* const* d_in, const int* in_sizes, int n_in,
                              void* d_out, int out_size, void* d_ws, size_t ws_size,
                              hipStream_t stream) {
  const float* x        = (const float*)d_in[0];
  const float* w_patch  = (const float*)d_in[1];
  const float* b_patch  = (const float*)d_in[2];
  const float* cls_tok  = (const float*)d_in[3];
  const float* pos_emb  = (const float*)d_in[4];
  const float* ln1_g    = (const float*)d_in[5];
  const float* ln1_b    = (const float*)d_in[6];
  const float* w_qkv    = (const float*)d_in[7];
  const float* w_proj   = (const float*)d_in[8];
  const float* b_proj   = (const float*)d_in[9];
  const float* ln2_g    = (const float*)d_in[10];
  const float* ln2_b    = (const float*)d_in[11];
  const float* w_fc1    = (const float*)d_in[12];
  const float* b_fc1    = (const float*)d_in[13];
  const float* w_fc2    = (const float*)d_in[14];
  const float* b_fc2    = (const float*)d_in[15];
  const float* w_gate   = (const float*)d_in[16];
  const float* w_e1     = (const float*)d_in[17];
  const float* b_e1     = (const float*)d_in[18];
  const float* w_e2     = (const float*)d_in[19];
  const float* b_e2     = (const float*)d_in[20];
  const float* ln_f_g   = (const float*)d_in[21];
  const float* ln_f_b   = (const float*)d_in[22];
  const float* w_head   = (const float*)d_in[23];
  const float* b_head   = (const float*)d_in[24];
  float* out = (float*)d_out;
  (void)in_sizes; (void)n_in; (void)out_size; (void)ws_size;

  // ---- workspace layout ----
  float* fp = (float*)d_ws;
  float* h      = fp;                          fp += (size_t)TT*DD;
  float* xln    = fp;                          fp += (size_t)TT*DD;
  float* moeout = fp;                          fp += (size_t)TT*2*DD;
  float* clsln  = fp;                          fp += (size_t)8*DD;
  float* g01    = fp;                          fp += (size_t)TT*2;
  float* gate_l = fp;                          fp += (size_t)MAXA;
  int* ip = (int*)fp;
  int* e01    = ip;                            ip += TT*2;
  int* cnt    = ip;                            ip += 8;
  int* cnt2   = ip;                            ip += 8;
  int* offs   = ip;                            ip += 16;
  int* tok_l  = ip;                            ip += MAXA;
  int* slot_l = ip;                            ip += MAXA;
  bf16_t* bp = (bf16_t*)ip;
  bf16_t* pm_bf   = bp;                        bp += (size_t)TP*DD;
  bf16_t* xln_bf  = bp;                        bp += (size_t)TT*DD;
  bf16_t* qkv_bf  = bp;                        bp += (size_t)TT*QKVN;
  bf16_t* attnb   = bp;                        bp += (size_t)TT*DD;
  bf16_t* hid     = bp;                        bp += (size_t)MAXA*HID;
  bf16_t* wT_patch= bp;                        bp += (size_t)DD*DD;
  bf16_t* wT_qkv  = bp;                        bp += (size_t)DD*QKVN;
  bf16_t* wT_proj = bp;                        bp += (size_t)DD*DD;
  bf16_t* wT_big  = bp;                        bp += (size_t)NEXP*DD*HID;

  // ---- patch embedding ----
  tcast_k<<<dim3(DD/32, DD/32, 1), dim3(32,8), 0, stream>>>(w_patch, wT_patch, DD, DD);
  patchify_k<<<(TP*DD + 255)/256, 256, 0, stream>>>(x, pm_bf);
  mgemm_k<<<dim3(DD/128, (TP+127)/128), 256, 0, stream>>>(
      pm_bf, wT_patch, b_patch, nullptr, xln, nullptr, TP, DD, DD, F_BIAS,
      nullptr, nullptr, nullptr, nullptr, nullptr, nullptr);
  assemble_k<<<(TT*DD + 255)/256, 256, 0, stream>>>(xln, cls_tok, pos_emb, h);

  const int MT = (TT + 127) / 128;   // 13 row tiles
  for (int i = 0; i < 4; i++) {
    int j = i >> 1;
    // attention
    tcast_k<<<dim3(QKVN/32, DD/32, 1), dim3(32,8), 0, stream>>>(
        w_qkv + (size_t)i*DD*QKVN, wT_qkv, DD, QKVN);
    tcast_k<<<dim3(DD/32, DD/32, 1), dim3(32,8), 0, stream>>>(
        w_proj + (size_t)i*DD*DD, wT_proj, DD, DD);
    ln_k<<<TT, 256, 0, stream>>>(h, DD, ln1_g + (size_t)i*DD, ln1_b + (size_t)i*DD,
                                 xln, xln_bf, TT);
    mgemm_k<<<dim3(QKVN/128, MT), 256, 0, stream>>>(
        xln_bf, wT_qkv, nullptr, nullptr, nullptr, qkv_bf, TT, QKVN, DD, F_OUTBF,
        nullptr, nullptr, nullptr, nullptr, nullptr, nullptr);
    fattn_k<<<dim3(4, BB*NHEAD), 256, 0, stream>>>(qkv_bf, attnb);
    mgemm_k<<<dim3(DD/128, MT), 256, 0, stream>>>(
        attnb, wT_proj, b_proj + (size_t)i*DD, h, h, nullptr, TT, DD, DD,
        F_BIAS | F_RESID, nullptr, nullptr, nullptr, nullptr, nullptr, nullptr);
    // mlp / moe
    ln_k<<<TT, 256, 0, stream>>>(h, DD, ln2_g + (size_t)i*DD, ln2_b + (size_t)i*DD,
                                 xln, xln_bf, TT);
    if ((i & 1) == 0) {
      tcast_k<<<dim3(HID/32, DD/32, 1), dim3(32,8), 0, stream>>>(
          w_fc1 + (size_t)j*DD*HID, wT_big, DD, HID);
      mgemm_k<<<dim3(HID/128, MT), 256, 0, stream>>>(
          xln_bf, wT_big, b_fc1 + (size_t)j*HID, nullptr, nullptr, hid,
          TT, HID, DD, F_BIAS | F_GELU | F_OUTBF,
          nullptr, nullptr, nullptr, nullptr, nullptr, nullptr);
      tcast_k<<<dim3(DD/32, HID/32, 1), dim3(32,8), 0, stream>>>(
          w_fc2 + (size_t)j*HID*DD, wT_big, HID, DD);
      mgemm_k<<<dim3(DD/128, MT), 256, 0, stream>>>(
          hid, wT_big, b_fc2 + (size_t)j*DD, h, h, nullptr, TT, DD, HID,
          F_BIAS | F_RESID, nullptr, nullptr, nullptr, nullptr, nullptr, nullptr);
    } else {
      zero_k<<<1, 64, 0, stream>>>(cnt);
      gate_k<<<(TT+63)/64, 64, 0, stream>>>(xln, w_gate + (size_t)j*DD*NEXP, e01, g01, cnt);
      offs_k<<<1, 32, 0, stream>>>(cnt, offs);
      scatter_k<<<(TT+63)/64, 64, 0, stream>>>(e01, g01, offs, cnt2, tok_l, gate_l, slot_l);
      tcast_k<<<dim3(HID/32, DD/32, NEXP), dim3(32,8), 0, stream>>>(
          w_e1 + (size_t)j*NEXP*DD*HID, wT_big, DD, HID);
      mgemm_k<<<dim3(HID/128, NAT), 256, 0, stream>>>(
          xln_bf, wT_big, b_e1 + (size_t)j*NEXP*HID, nullptr, nullptr, hid,
          0, HID, DD, F_MOE | F_GATHER | F_BIAS | F_GELU | F_OUTBF,
          offs, cnt, tok_l, nullptr, nullptr, nullptr);
      tcast_k<<<dim3(DD/32, HID/32, NEXP), dim3(32,8), 0, stream>>>(
          w_e2 + (size_t)j*NEXP*HID*DD, wT_big, HID, DD);
      mgemm_k<<<dim3(DD/128, NAT), 256, 0, stream>>>(
          hid, wT_big, b_e2 + (size_t)j*NEXP*DD, nullptr, nullptr, nullptr,
          0, DD, HID, F_MOE | F_SCATTER | F_BIAS,
          offs, cnt, tok_l, slot_l, gate_l, moeout);
      combine_k<<<(TT*DD + 255)/256, 256, 0, stream>>>(moeout, h);
    }
  }

  ln_k<<<8, 256, 0, stream>>>(h, (size_t)NTOK*DD, ln_f_g, ln_f_b, clsln, nullptr, 8);
  head_k<<<(BB*NCLS + 255)/256, 256, 0, stream>>>(clsln, w_head, b_head, out);
}